// Round 17
// baseline (52.664 us; speedup 1.0000x reference)
//
#include <hip/hip_runtime.h>

#define SUBS  64
#define GUARD 256              // left guard halves (32 tiles) [fallback path]
#define LB    32               // IIR block length (rows per run/wave)
#define JT    8                // history terms: 8*32 = 256 >= 200-tap support
#define LSTR  136              // k_mm LDS row stride (halves)

typedef _Float16 f16x8 __attribute__((ext_vector_type(8)));
typedef float    f32x4 __attribute__((ext_vector_type(4)));

__device__ inline f16x8 ld_frag(const float* p) {
    float4 a = *(const float4*)p;
    float4 b = *(const float4*)(p + 4);
    f16x8 f;
    f[0]=(_Float16)a.x; f[1]=(_Float16)a.y; f[2]=(_Float16)a.z; f[3]=(_Float16)a.w;
    f[4]=(_Float16)b.x; f[5]=(_Float16)b.y; f[6]=(_Float16)b.z; f[7]=(_Float16)b.w;
    return f;
}
__device__ inline uint pkh2(float a, float b) {
    union { _Float16 h[2]; uint u; } p;
    p.h[0] = (_Float16)a; p.h[1] = (_Float16)b; return p.u;
}

// IIR core: per basis, z[m] = 2r z[m-1] - r^2 z[m-2] + cr*x[m-1]
#define STEP3(u)                                                                 \
    _Pragma("unroll")                                                            \
    for (int b = 0; b < 3; ++b) {                                                \
        const float yn = fmaf(twr[b], y1[b], fmaf(mr2[b], y2[b], cr[b] * (u)));  \
        y2[b] = y1[b]; y1[b] = yn;                                               \
    }
#define PAIRW(wrd) {                                                             \
    union { uint u; _Float16 h[2]; } w_; w_.u = (wrd);                           \
    STEP3((float)w_.h[0]);                                                       \
    STEP3((float)w_.h[1]); }

// ---------------------------------------------------------------------------
// Kernel 1: MFMA Zc=(Z@C^T), base=(Y@C^T)+S+theta (f16) into transposed tiled
// layout [tile][64 s][8 halves]; fused from-rest 32-step state run per wave
// (straight from LDS) -> packed fb[run][lane][8]. Partial tail tiles are
// zero-filled. Zt/Bt guard zeroing only on the dl!=0 fallback.
// ---------------------------------------------------------------------------
__global__ __launch_bounds__(256, 4) void k_mm(
    const float* __restrict__ Z, const float* __restrict__ Y,
    const float* __restrict__ S, const float* __restrict__ C,
    const float* __restrict__ theta,
    const float* __restrict__ K_spike, const float* __restrict__ tau_spike,
    const float* __restrict__ delta_spike,
    _Float16* __restrict__ Zt, _Float16* __restrict__ Bt,
    float* __restrict__ fb, int T, int rgz, int NB)
{
    __shared__ _Float16 ztl[SUBS * LSTR];
    __shared__ _Float16 ytl[SUBS * LSTR];
    const int tid  = threadIdx.x;
    const int lane = tid & 63;
    const int wv   = tid >> 6;
    const int lr   = lane & 15;
    const int lg   = lane >> 4;
    const int t0b  = blockIdx.x * 128;

    int dl = (int)rintf(delta_spike[lane]);
    dl = min(max(dl, 0), 30);
    const bool alldl0 = __all(dl == 0);

    if (blockIdx.x == 0) {                    // fb guard runs (-8..-1)
        for (int idx = tid; idx < JT * 512; idx += 256) fb[idx] = 0.f;
    }
    if (!alldl0) {                            // guards only for fallback path
        if (blockIdx.x < 8) {
            const int tile = blockIdx.x * 4 + wv;
            uint4 z4 = {0, 0, 0, 0};
            ((uint4*)Zt)[(size_t)tile * 64 + lane] = z4;
            ((uint4*)Bt)[(size_t)tile * 64 + lane] = z4;
        } else if (blockIdx.x < 18) {
            const int tile = rgz + (blockIdx.x - 8) * 4 + wv;
            uint4 z4 = {0, 0, 0, 0};
            ((uint4*)Zt)[(size_t)tile * 64 + lane] = z4;
            ((uint4*)Bt)[(size_t)tile * 64 + lane] = z4;
        }
    }

    f16x8 bfr[4][2];
    #pragma unroll
    for (int nt = 0; nt < 4; ++nt)
        #pragma unroll
        for (int ks = 0; ks < 2; ++ks)
            bfr[nt][ks] = ld_frag(&C[(lr + 16 * nt) * 64 + ks * 32 + lg * 8]);

    float th4[4];
    #pragma unroll
    for (int nt = 0; nt < 4; ++nt) th4[nt] = theta[lr + 16 * nt];

    #pragma unroll
    for (int g = 0; g < 2; ++g) {
        const int t0 = t0b + wv * 32 + g * 16;
        const int rowA = t0 + lr;
        const bool okA = rowA < T;
        f16x8 az[2], ay[2];
        #pragma unroll
        for (int ks = 0; ks < 2; ++ks) {
            if (okA) {
                az[ks] = ld_frag(&Z[(size_t)rowA * 64 + ks * 32 + lg * 8]);
                ay[ks] = ld_frag(&Y[(size_t)rowA * 64 + ks * 32 + lg * 8]);
            } else {
                az[ks] = (f16x8)(_Float16)0.f;
                ay[ks] = (f16x8)(_Float16)0.f;
            }
        }

        f32x4 accZ[4], accY[4];
        #pragma unroll
        for (int nt = 0; nt < 4; ++nt) { accZ[nt] = (f32x4){0,0,0,0}; accY[nt] = (f32x4){0,0,0,0}; }
        #pragma unroll
        for (int nt = 0; nt < 4; ++nt) {
            #pragma unroll
            for (int ks = 0; ks < 2; ++ks) {
                accZ[nt] = __builtin_amdgcn_mfma_f32_16x16x32_f16(az[ks], bfr[nt][ks], accZ[nt], 0, 0, 0);
                accY[nt] = __builtin_amdgcn_mfma_f32_16x16x32_f16(ay[ks], bfr[nt][ks], accY[nt], 0, 0, 0);
            }
        }

        // fold S + theta into accY (fragment-pattern loads, 4x64B segments)
        #pragma unroll
        for (int nt = 0; nt < 4; ++nt) {
            const int sc = lr + 16 * nt;
            #pragma unroll
            for (int r = 0; r < 4; ++r) {
                const int t = t0 + lg * 4 + r;
                if (t < T) accY[nt][r] += S[(size_t)t * 64 + sc] + th4[nt];
            }
        }

        #pragma unroll
        for (int nt = 0; nt < 4; ++nt) {
            const int sc = lr + 16 * nt;
            const int lt = wv * 32 + g * 16 + lg * 4;
            uint2 pz, py;
            pz.x = pkh2(accZ[nt][0], accZ[nt][1]);
            pz.y = pkh2(accZ[nt][2], accZ[nt][3]);
            py.x = pkh2(accY[nt][0], accY[nt][1]);
            py.y = pkh2(accY[nt][2], accY[nt][3]);
            *(uint2*)&ztl[sc * LSTR + lt] = pz;
            *(uint2*)&ytl[sc * LSTR + lt] = py;
        }
    }

    __syncthreads();

    // cooperative tiled stores (row = s fastest -> coalesced); tail zero-fill
    const int gbase = (GUARD >> 3) + blockIdx.x * 16;
    #pragma unroll
    for (int it = 0; it < 4; ++it) {
        const int chunk = it * 256 + tid;
        const int row = chunk & 63;
        const int col = chunk >> 6;
        const int tb  = t0b + col * 8;
        if (tb + 7 < T) {
            ((uint4*)Zt)[(size_t)(gbase + col) * 64 + row] =
                *(const uint4*)&ztl[row * LSTR + col * 8];
            ((uint4*)Bt)[(size_t)(gbase + col) * 64 + row] =
                *(const uint4*)&ytl[row * LSTR + col * 8];
        } else {
            union { ushort u[8]; uint4 v; } vz, vb;
            #pragma unroll
            for (int h = 0; h < 8; ++h) {
                const bool ok = (tb + h < T);
                vz.u[h] = ok ? ((const ushort*)ztl)[row * LSTR + col * 8 + h] : (ushort)0;
                vb.u[h] = ok ? ((const ushort*)ytl)[row * LSTR + col * 8 + h] : (ushort)0;
            }
            ((uint4*)Zt)[(size_t)(gbase + col) * 64 + row] = vz.v;
            ((uint4*)Bt)[(size_t)(gbase + col) * 64 + row] = vb.v;
        }
    }

    // fused from-rest state run: wave wv handles run grun = blk*4 + wv
    const int grun = blockIdx.x * 4 + wv;
    if (grun < NB) {
        float twr[3], mr2[3], cr[3];
        #pragma unroll
        for (int b = 0; b < 3; ++b) {
            const float tau = __expf(tau_spike[b]);
            const float r   = __expf(-1.0f / tau);
            twr[b] = 2.0f * r;
            mr2[b] = -r * r;
            cr[b]  = K_spike[lane * 3 + b] / tau * r;
        }
        const uint* zr = (const uint*)ztl + lane * (LSTR / 2) + wv * 16;
        float y1[3] = {0.f, 0.f, 0.f}, y2[3] = {0.f, 0.f, 0.f};
        #pragma unroll
        for (int k = 0; k < 16; ++k) PAIRW(zr[k]);
        float* fout = fb + (size_t)(grun + JT) * 512 + lane * 8;
        *(float4*)fout       = make_float4(y1[0], y2[0], y1[1], y2[1]);
        *(float2*)(fout + 4) = make_float2(y1[2], y2[2]);
    }
}

// ---------------------------------------------------------------------------
// Kernel 2: compose v[32i] = sum_{j=1..8} M^{32(j-1)} f_{i-j} (Horner,
// closed-form M^32) from packed fb, then 30 steps over 4 aligned x tiles;
// out = sigmoid(Bt + filtered)*W + Vo. 24 loads/wave, no LDS.
// ---------------------------------------------------------------------------
#define EMIT(o, f) {                                                             \
    const int t_ = t0 + (o);                                                     \
    if (t_ < T) {                                                                \
        union { uint u; _Float16 h[2]; } wb_; wb_.u = bwd[(o) >> 1];             \
        const float xin_ = (float)wb_.h[(o) & 1] + (f);                          \
        const float sig_ = 1.0f / (1.0f + __expf(-xin_));                        \
        out[(size_t)t_ * 64 + s] = fmaf(sig_, wsub, vo);                         \
    } }

__global__ __launch_bounds__(256, 4) void k_iir2(
    const _Float16* __restrict__ Zt, const _Float16* __restrict__ Bt,
    const float* __restrict__ K_spike, const float* __restrict__ tau_spike,
    const float* __restrict__ delta_spike,
    const float* __restrict__ W, const float* __restrict__ Vo,
    const float* __restrict__ fb, float* __restrict__ out, int T, int NB)
{
    const int tid = threadIdx.x;
    const int s   = tid & 63;
    const int wv  = tid >> 6;
    const int i   = blockIdx.x * 4 + wv;
    if (i >= NB) return;
    const int t0 = i * LB;

    float twr[3], mr2[3], cr[3], taus[3];
    #pragma unroll
    for (int b = 0; b < 3; ++b) {
        const float tau = __expf(tau_spike[b]);
        taus[b] = tau;
        const float r = __expf(-1.0f / tau);
        twr[b] = 2.0f * r;
        mr2[b] = -r * r;
        cr[b]  = K_spike[s * 3 + b] / tau * r;
    }
    int dl = (int)rintf(delta_spike[s]);
    dl = min(max(dl, 0), 30);
    const float wsub = W[s];
    const float vo   = Vo[0];

    if (__all(dl == 0)) {
        // M^32 per basis: z[n+k] = (k+1) r^k z[n] - k r^(k+1) z[n-1]
        float aL[3], bL[3], cL[3], dL[3];
        #pragma unroll
        for (int b = 0; b < 3; ++b) {
            const float r   = 0.5f * twr[b];
            const float rm1 = __expf(-(float)(LB - 1) / taus[b]);  // r^31
            const float rl  = rm1 * r;                             // r^32
            const float rp  = rl * r;                              // r^33
            aL[b] = (float)(LB + 1) * rl;
            bL[b] = -(float)LB * rp;
            cL[b] = (float)LB * rm1;
            dL[b] = -(float)(LB - 1) * rl;
        }
        float y1[3], y2[3];
        {   // f_{i-8}
            const float* fq = fb + (size_t)i * 512 + s * 8;
            const float4 lo = *(const float4*)fq;
            const float2 hi = *(const float2*)(fq + 4);
            y1[0] = lo.x; y2[0] = lo.y; y1[1] = lo.z; y2[1] = lo.w;
            y1[2] = hi.x; y2[2] = hi.y;
        }
        #pragma unroll
        for (int j = 7; j >= 1; --j) {
            const float* fq = fb + (size_t)(i + JT - j) * 512 + s * 8;
            const float4 lo = *(const float4*)fq;
            const float2 hi = *(const float2*)(fq + 4);
            const float f1[3] = { lo.x, lo.z, hi.x };
            const float f2[3] = { lo.y, lo.w, hi.y };
            #pragma unroll
            for (int b = 0; b < 3; ++b) {
                const float n1 = fmaf(aL[b], y1[b], fmaf(bL[b], y2[b], f1[b]));
                const float n2 = fmaf(cL[b], y1[b], fmaf(dL[b], y2[b], f2[b]));
                y1[b] = n1; y2[b] = n2;
            }
        }

        const uint4* xb = (const uint4*)Zt + (size_t)(32 + 4 * i) * 64 + s;
        const uint4 x0 = xb[0], x1 = xb[64], x2 = xb[128], x3 = xb[192];
        const uint4* bb = (const uint4*)Bt + (size_t)(32 + 4 * i) * 64 + s;
        const uint4 b0 = bb[0], b1 = bb[64], b2 = bb[128], b3 = bb[192];

        const uint xw[15]  = { x0.x, x0.y, x0.z, x0.w, x1.x, x1.y, x1.z, x1.w,
                               x2.x, x2.y, x2.z, x2.w, x3.x, x3.y, x3.z };
        const uint bwd[16] = { b0.x, b0.y, b0.z, b0.w, b1.x, b1.y, b1.z, b1.w,
                               b2.x, b2.y, b2.z, b2.w, b3.x, b3.y, b3.z, b3.w };

        EMIT(0, y2[0] + y2[1] + y2[2]);
        EMIT(1, y1[0] + y1[1] + y1[2]);
        #pragma unroll
        for (int w = 0; w < 15; ++w) {
            union { uint u; _Float16 h[2]; } wx; wx.u = xw[w];
            STEP3((float)wx.h[0]);
            EMIT(2 + 2 * w, y1[0] + y1[1] + y1[2]);
            STEP3((float)wx.h[1]);
            EMIT(3 + 2 * w, y1[0] + y1[1] + y1[2]);
        }
    } else {
        // generic per-lane-delay path (Bt already includes S+theta)
        float y1[3] = {0.f, 0.f, 0.f}, y2[3] = {0.f, 0.f, 0.f};
        const int xi0 = t0 - 226 - dl;
        for (int k = 0; k < 224 + LB; ++k) {
            const int h = GUARD + xi0 + k;
            const float u = (float)Zt[(size_t)(h >> 3) * 512 + s * 8 + (h & 7)];
            STEP3(u);
            const int o = k - 224;
            if (o >= 0) {
                const int t = t0 + o;
                if (t < T) {
                    const int hy = GUARD + t;
                    const float bv = (float)Bt[(size_t)(hy >> 3) * 512 + s * 8 + (hy & 7)];
                    const float xin = bv + y1[0] + y1[1] + y1[2];
                    const float sig = 1.0f / (1.0f + __expf(-xin));
                    out[(size_t)t * 64 + s] = fmaf(sig, wsub, vo);
                }
            }
        }
    }
}

// ---------------------------------------------------------------------------
extern "C" void kernel_launch(void* const* d_in, const int* in_sizes, int n_in,
                              void* d_out, int out_size, void* d_ws, size_t ws_size,
                              hipStream_t stream)
{
    const float* S     = (const float*)d_in[0];
    const float* Y     = (const float*)d_in[1];
    const float* Z     = (const float*)d_in[2];
    const float* C     = (const float*)d_in[3];
    const float* Vo    = (const float*)d_in[4];
    const float* W     = (const float*)d_in[5];
    const float* theta = (const float*)d_in[6];
    const float* K     = (const float*)d_in[7];
    const float* tau   = (const float*)d_in[8];
    const float* delta = (const float*)d_in[9];
    const int T  = in_sizes[0] / SUBS;
    const int NB = (T + LB - 1) / LB;

    const int rgz    = (GUARD + T + 7) >> 3;
    const int ntiles = rgz + 44;
    _Float16* Zt = (_Float16*)d_ws;
    _Float16* Bt = (_Float16*)((char*)d_ws + (size_t)ntiles * 1024);
    float*    fb = (float*)((char*)d_ws + (size_t)ntiles * 2048);

    k_mm<<<(T + 127) / 128, 256, 0, stream>>>(Z, Y, S, C, theta, K, tau, delta,
                                              Zt, Bt, fb, T, rgz, NB);
    k_iir2<<<(NB + 3) / 4, 256, 0, stream>>>(Zt, Bt, K, tau, delta, W, Vo, fb,
                                             (float*)d_out, T, NB);
}